// Round 4
// baseline (288.102 us; speedup 1.0000x reference)
//
#include <hip/hip_runtime.h>
#include <hip/hip_bf16.h>

// ---------------------------------------------------------------------------
// AttentionModel B=4,S=2048,E=1024 single-head, fp32 in/out. bf16 MFMA GEMMs.
// R11: recombine measured-best pieces.
//  - qkv: REVERTED to R7 128x128 / 1536-block kernel (57.7us measured; the
//    256-tile 1-blk/CU variants measured 62-74us -- multi-block/CU implicit
//    overlap beats 8-wave single-block pipelining for this shape).
//  - scores: keep R10 scores_v3 (256x128 3-slot ring, 512 blk = 2 exact
//    rounds; measured ~5us better than R7 scores).
//  - PV: NEW pv_v3 on the templated v3 ring core: 256x128 tiles, K=2048
//    (NT=32), 8by x 8bx x 4bz = 256 blocks = 1 exact round, rowsum folded
//    via ones-MFMA (R7-verified trick).
// Pipeline: prep -> qkv_proj (1536) -> scores_v3 (512) -> pv_v3 (256).
// ---------------------------------------------------------------------------

typedef __bf16 bf16_t;
typedef bf16_t bf16x8 __attribute__((ext_vector_type(8)));
typedef bf16_t bf16x4 __attribute__((ext_vector_type(4)));
typedef float  f32x4  __attribute__((ext_vector_type(4)));

typedef const __attribute__((address_space(1))) unsigned gl_uint;
typedef __attribute__((address_space(3))) unsigned lds_uint;

#define BM 128
#define BN 128
#define BK 64

__device__ __forceinline__ void gload_lds16(const void* g, void* l) {
  __builtin_amdgcn_global_load_lds((gl_uint*)g, (lds_uint*)l, 16, 0, 0);
}

#define VMCNT(N) asm volatile("s_waitcnt vmcnt(" #N ")" ::: "memory")
#define LGKM0()  asm volatile("s_waitcnt lgkmcnt(0)" ::: "memory")

// ===========================================================================
// v3 core: 256x128 tile, K = NT*64 (KS = row stride in elements), 512 thr
// (8 waves as 4Mx2N, per-wave 64x64, acc[4][4]). LDS: 3 ring slots x
// (A 256x64 + B 128x64) = 144 KiB. Rows 64 bf16 = 8 x 16B slots, XOR-
// swizzled (slot c holds global seg c^(row&7)) -- verified conflict-free.
// iter kt: STAGE(kt+3 -> slot kt%3); RD frags(kt+1); MFMA(kt) from regs;
//          VMCNT(6); s_barrier.   (counted vmcnt: 2 tiles always in flight)
// LSUM: acc_l[mi] += fa[mi][kk] . ones  (row sums, C-layout row mapping).
// ===========================================================================
template <int KS, int NT, bool LSUM>
__device__ __forceinline__ void gemm_v3(
    const bf16_t* __restrict__ Ab, const bf16_t* __restrict__ Bb,
    bf16_t* Lb, f32x4 acc[4][4], f32x4 acc_l[4])
{
  const int tid  = threadIdx.x;
  const int lane = tid & 63;
  const int l15  = lane & 15;
  const int quad = lane >> 4;
  const int wid  = tid >> 6;
  const int wr   = wid >> 1;          // 0..3 (M quarter, 64 rows)
  const int wcl  = wid & 1;           // 0..1 (N half, 64 cols)
  const int swz0 = (quad ^ (l15 & 7)) * 8;
  const int swz1 = ((quad + 4) ^ (l15 & 7)) * 8;

  bf16x8 ones;
#pragma unroll
  for (int t = 0; t < 8; ++t) ones[t] = (bf16_t)1.0f;

  // Staging offsets: unit = 64 rows (8KB). row = u*64 + (tid>>3);
  // seg = (tid&7)^(row&7) = (tid&7)^((tid>>3)&7) since 64%8==0.
  const int r8 = tid >> 3, s8 = tid & 7;
  const size_t gbase = (size_t)r8 * KS + (size_t)((s8 ^ (r8 & 7)) * 8);
  const int dbase = tid * 8;          // elements (16B per thread)

#define SLOTA(s) (Lb + (s) * 24576)
#define SLOTB(s) (Lb + (s) * 24576 + 16384)
#define STAGE6(ktile, slot) { \
    const bf16_t* _A = Ab + (size_t)(ktile) * 64; \
    const bf16_t* _B = Bb + (size_t)(ktile) * 64; \
    bf16_t* _la = SLOTA(slot); bf16_t* _lb = SLOTB(slot); \
    gload_lds16(_A + gbase,                      _la + dbase); \
    gload_lds16(_A + gbase + (size_t)64 * KS,    _la + dbase + 4096); \
    gload_lds16(_A + gbase + (size_t)128 * KS,   _la + dbase + 8192); \
    gload_lds16(_A + gbase + (size_t)192 * KS,   _la + dbase + 12288); \
    gload_lds16(_B + gbase,                      _lb + dbase); \
    gload_lds16(_B + gbase + (size_t)64 * KS,    _lb + dbase + 4096); }

  const int aoff = (wr * 64 + l15) * 64;
  const int boff = (wcl * 64 + l15) * 64;

#define RD(slot, FA, FB) { \
    const bf16_t* _a = SLOTA(slot) + aoff; \
    const bf16_t* _b = SLOTB(slot) + boff; \
    _Pragma("unroll") for (int mi = 0; mi < 4; ++mi) { \
      FA[mi][0] = *(const bf16x8*)(_a + mi * 1024 + swz0); \
      FA[mi][1] = *(const bf16x8*)(_a + mi * 1024 + swz1); } \
    _Pragma("unroll") for (int ni = 0; ni < 4; ++ni) { \
      FB[ni][0] = *(const bf16x8*)(_b + ni * 1024 + swz0); \
      FB[ni][1] = *(const bf16x8*)(_b + ni * 1024 + swz1); } }

#define MFM(FA, FB) { \
    _Pragma("unroll") for (int kk = 0; kk < 2; ++kk) { \
      _Pragma("unroll") for (int mi = 0; mi < 4; ++mi) \
      _Pragma("unroll") for (int ni = 0; ni < 4; ++ni) \
        acc[mi][ni] = __builtin_amdgcn_mfma_f32_16x16x32_bf16( \
            FA[mi][kk], FB[ni][kk], acc[mi][ni], 0, 0, 0); \
      if constexpr (LSUM) { \
        _Pragma("unroll") for (int mi = 0; mi < 4; ++mi) \
          acc_l[mi] = __builtin_amdgcn_mfma_f32_16x16x32_bf16( \
              FA[mi][kk], ones, acc_l[mi], 0, 0, 0); } } }

  bf16x8 fa0[4][2], fb0[4][2], fa1[4][2], fb1[4][2];

  // Prologue: stage k-tiles 0,1,2 into slots 0,1,2 (18 loads).
  STAGE6(0, 0); STAGE6(1, 1); STAGE6(2, 2);
  VMCNT(6);                         // tiles 0,1 landed; tile 2 in flight
  __builtin_amdgcn_s_barrier();
  RD(0, fa0, fb0);                  // frags(0)
  LGKM0();
  __builtin_amdgcn_s_barrier();

  // Main loop (fully unrolled; slot / parity / predicates compile-time).
#pragma unroll
  for (int kt = 0; kt < NT - 2; ++kt) {
    const int ss = kt % 3;          // stage slot (holds kt, dead since kt-1)
    const int rs = (kt + 1) % 3;    // read slot (kt+1, landed+barrier'd)
    if (kt <= NT - 4) STAGE6(kt + 3, ss);
    if ((kt & 1) == 0) { RD(rs, fa1, fb1); MFM(fa0, fb0); }
    else               { RD(rs, fa0, fb0); MFM(fa1, fb1); }
    if (kt <= NT - 4) { VMCNT(6); }   // kt+2 landed; kt+3 stays in flight
    else              { VMCNT(0); }   // last loop iter: tile NT-1 landed
    __builtin_amdgcn_s_barrier();
  }
  // kt=NT-2 (even): read frags(NT-1), MFMA frags(NT-2); then final MFMA.
  RD((NT - 1) % 3, fa1, fb1); MFM(fa0, fb0);
  MFM(fa1, fb1);

#undef SLOTA
#undef SLOTB
#undef STAGE6
#undef RD
#undef MFM
}

// ===========================================================================
// R7 128x128 core (qkv) -- verified, conflict-free, 57.7us measured.
// ===========================================================================
__device__ __forceinline__ void mfma_tile128(const bf16_t* As, const bf16_t* Bs,
                                             f32x4 acc[4][4]) {
  const int lane = threadIdx.x & 63;
  const int quad = lane >> 4;
  const int l15  = lane & 15;
  const int wid  = threadIdx.x >> 6;
  const int wm   = (wid >> 1) * 64;
  const int wn   = (wid & 1) * 64;
  const int csw  = l15 & 7;
#pragma unroll
  for (int ks = 0; ks < 2; ++ks) {
    const int sg = ks * 4 + quad;
    const int c  = (sg ^ csw) * 8;
    bf16x8 fa[4], fb[4];
#pragma unroll
    for (int i = 0; i < 4; ++i)
      fa[i] = *(const bf16x8*)&As[(wm + i * 16 + l15) * BK + c];
#pragma unroll
    for (int i = 0; i < 4; ++i)
      fb[i] = *(const bf16x8*)&Bs[(wn + i * 16 + l15) * BK + c];
#pragma unroll
    for (int mi = 0; mi < 4; ++mi)
#pragma unroll
      for (int ni = 0; ni < 4; ++ni)
        acc[mi][ni] = __builtin_amdgcn_mfma_f32_16x16x32_bf16(
            fa[mi], fb[ni], acc[mi][ni], 0, 0, 0);
  }
}

__device__ __forceinline__ void gemm_core128(
    const bf16_t* __restrict__ Ab, const bf16_t* __restrict__ Bb,
    const int K, bf16_t* As, bf16_t* Bs, f32x4 acc[4][4])
{
  const int tid = threadIdx.x;
  for (int kt = 0; kt < K; kt += BK) {
#pragma unroll
    for (int j = 0; j < 4; ++j) {
      const int lin = j * 256 + tid;
      const int row = lin >> 3;
      const int seg = (lin & 7) ^ (row & 7);
      gload_lds16(Ab + (size_t)row * K + kt + seg * 8, &As[lin * 8]);
    }
#pragma unroll
    for (int j = 0; j < 4; ++j) {
      const int lin = j * 256 + tid;
      const int row = lin >> 3;
      const int seg = (lin & 7) ^ (row & 7);
      gload_lds16(Bb + (size_t)row * K + kt + seg * 8, &Bs[lin * 8]);
    }
    __syncthreads();
    mfma_tile128(As, Bs, acc);
    __syncthreads();
  }
}

// Fused Q/K/V projection (bf16 A and W). 1536 blocks, 1-D grid. (R7)
__global__ __launch_bounds__(256, 2)
void qkv_proj(const bf16_t* __restrict__ qb, const bf16_t* __restrict__ kb,
              const bf16_t* __restrict__ vb, const bf16_t* __restrict__ Wqt,
              const bf16_t* __restrict__ Wkt, const bf16_t* __restrict__ Wvt,
              const float* __restrict__ bq, const float* __restrict__ bk,
              const float* __restrict__ bv, bf16_t* __restrict__ qp,
              bf16_t* __restrict__ kp, bf16_t* __restrict__ vT)
{
  __shared__ __align__(16) bf16_t As[BM * BK];
  __shared__ __align__(16) bf16_t Bs[BN * BK];

  const int L = blockIdx.x;
  const int g = L >> 3;
  const int gst = (L & 7) * 3 + (g >> 6);   // [0,24)
  const int z  = gst >> 3;
  const int sy = gst & 7;
  const int w  = g & 63;
  const int bx = w & 7;
  const int by = sy * 8 + (w >> 3);

  const bf16_t* A    = (z == 0) ? qb : (z == 1) ? kb : vb;
  const bf16_t* W    = (z == 0) ? Wqt : (z == 1) ? Wkt : Wvt;
  const float*  bias = (z == 0) ? bq : (z == 1) ? bk : bv;
  const int K = 1024, N = 1024;
  const bf16_t* Ab = A + (size_t)by * BM * K;
  const bf16_t* Bb = W + (size_t)bx * BN * K;

  f32x4 acc[4][4];
  const f32x4 z4 = {0.f, 0.f, 0.f, 0.f};
#pragma unroll
  for (int i = 0; i < 4; ++i)
#pragma unroll
    for (int j = 0; j < 4; ++j) acc[i][j] = z4;

  gemm_core128(Ab, Bb, K, As, Bs, acc);

  const int lane = threadIdx.x & 63;
  const int quad = lane >> 4;
  const int l15  = lane & 15;
  const int wid  = threadIdx.x >> 6;
  const int wm = (wid >> 1) * 64, wn = (wid & 1) * 64;
  const int m0 = by * BM, n0 = bx * BN;
#pragma unroll
  for (int mi = 0; mi < 4; ++mi) {
#pragma unroll
    for (int ni = 0; ni < 4; ++ni) {
      const int gn = n0 + wn + ni * 16 + l15;
      const int gm = m0 + wm + mi * 16 + quad * 4;
      const float bv_ = bias[gn];
      f32x4 a = acc[mi][ni];
      if (z < 2) {
        bf16_t* C = (z == 0) ? qp : kp;
#pragma unroll
        for (int r = 0; r < 4; ++r)
          C[(size_t)(gm + r) * N + gn] = (bf16_t)(a[r] + bv_);
      } else {
        const int b = gm >> 11;   // S=2048
        const int s = gm & 2047;
        bf16x4 o;
#pragma unroll
        for (int r = 0; r < 4; ++r) o[r] = (bf16_t)(a[r] + bv_);
        *(bf16x4*)&vT[((size_t)b * N + gn) * 2048 + s] = o;
      }
    }
  }
}

// scores: P = exp2(q.k^T * c), 256x128 tiles: 4 bz x 8 by x 16 bx = 512
// blocks (= 2 exact dispatch rounds).
__global__ __launch_bounds__(512, 2)
void scores_v3(const bf16_t* __restrict__ qp, const bf16_t* __restrict__ kp,
               bf16_t* __restrict__ P)
{
  __shared__ __align__(16) bf16_t lds[3 * 24576];   // 144 KiB
  const int L   = blockIdx.x;
  const int lin = (L & 7) * 64 + (L >> 3);   // bijective (512%8==0)
  const int bz  = lin >> 7;
  const int r   = lin & 127;
  const int by  = r >> 4, bx = r & 15;
  const int K = 1024;

  const bf16_t* Ab = qp + (size_t)bz * 2048 * 1024 + (size_t)by * 256 * K;
  const bf16_t* Bb = kp + (size_t)bz * 2048 * 1024 + (size_t)bx * 128 * K;

  f32x4 acc[4][4];
  f32x4 acc_l[4];
  const f32x4 z4 = {0.f, 0.f, 0.f, 0.f};
#pragma unroll
  for (int i = 0; i < 4; ++i) {
    acc_l[i] = z4;
#pragma unroll
    for (int j = 0; j < 4; ++j) acc[i][j] = z4;
  }

  gemm_v3<1024, 16, false>(Ab, Bb, lds, acc, acc_l);

  const int tid = threadIdx.x;
  const int lane = tid & 63, l15 = lane & 15, quad = lane >> 4;
  const int wid = tid >> 6, wr = wid >> 1, wcl = wid & 1;
  const int m0 = by * 256 + wr * 64;
  const int n0 = bx * 128 + wcl * 64;
  bf16_t* C = P + (size_t)bz * 2048 * 2048;
  const float cexp = 0.03125f * 1.4426950408889634f;  // (1/32)*log2(e)
#pragma unroll
  for (int mi = 0; mi < 4; ++mi) {
    const int gm = m0 + mi * 16 + quad * 4;
#pragma unroll
    for (int ni = 0; ni < 4; ++ni) {
      const int gn = n0 + ni * 16 + l15;
      f32x4 a = acc[mi][ni];
#pragma unroll
      for (int rr = 0; rr < 4; ++rr)
        C[(size_t)(gm + rr) * 2048 + gn] = (bf16_t)exp2f(a[rr] * cexp);
    }
  }
}

// PV: out = (P @ vT^T) / rowsum(P). 256x128 tiles, K=2048 (NT=32):
// 4 bz x 8 by x 8 bx = 256 blocks = 1 exact round. Rowsum via ones-MFMA.
__global__ __launch_bounds__(512, 2)
void pv_v3(const bf16_t* __restrict__ P, const bf16_t* __restrict__ vT,
           float* __restrict__ out)
{
  __shared__ __align__(16) bf16_t lds[3 * 24576];   // 144 KiB
  const int L   = blockIdx.x;
  const int lin = (L & 7) * 32 + (L >> 3);   // bijective (256%8==0)
  const int bz  = lin >> 6;
  const int r   = lin & 63;
  const int by  = r >> 3, bx = r & 7;

  const bf16_t* Ab = P  + (size_t)bz * 2048 * 2048 + (size_t)by * 256 * 2048;
  const bf16_t* Bb = vT + (size_t)bz * 1024 * 2048 + (size_t)bx * 128 * 2048;

  f32x4 acc[4][4];
  f32x4 acc_l[4];
  const f32x4 z4 = {0.f, 0.f, 0.f, 0.f};
#pragma unroll
  for (int i = 0; i < 4; ++i) {
    acc_l[i] = z4;
#pragma unroll
    for (int j = 0; j < 4; ++j) acc[i][j] = z4;
  }

  gemm_v3<2048, 32, true>(Ab, Bb, lds, acc, acc_l);

  const int tid = threadIdx.x;
  const int lane = tid & 63, l15 = lane & 15, quad = lane >> 4;
  const int wid = tid >> 6, wr = wid >> 1, wcl = wid & 1;
  const int m0 = by * 256 + wr * 64;
  const int n0 = bx * 128 + wcl * 64;
  float* C = out + (size_t)bz * 2048 * 1024;
#pragma unroll
  for (int mi = 0; mi < 4; ++mi) {
    const int gm = m0 + mi * 16 + quad * 4;
    float il[4];
#pragma unroll
    for (int rr = 0; rr < 4; ++rr) il[rr] = 1.0f / acc_l[mi][rr];
#pragma unroll
    for (int ni = 0; ni < 4; ++ni) {
      const int gn = n0 + ni * 16 + l15;
      f32x4 a = acc[mi][ni];
#pragma unroll
      for (int rr = 0; rr < 4; ++rr)
        C[(size_t)(gm + rr) * 1024 + gn] = a[rr] * il[rr];
    }
  }
}

// Merged prep: blocks [0,24576): fp32->bf16 cvt of q/k/v (1024 elem/block);
// blocks [24576,25344): 64x64 transpose-cvt tiles of Wq/Wk/Wv.
__global__ __launch_bounds__(256)
void prep(const float* __restrict__ q, const float* __restrict__ k,
          const float* __restrict__ v, const float* __restrict__ Wq,
          const float* __restrict__ Wk, const float* __restrict__ Wv,
          bf16_t* __restrict__ qo, bf16_t* __restrict__ ko,
          bf16_t* __restrict__ vo, bf16_t* __restrict__ Wqt,
          bf16_t* __restrict__ Wkt, bf16_t* __restrict__ Wvt) {
  const int L = blockIdx.x;
  const int tid = threadIdx.x;
  if (L < 24576) {
    const int z = L >> 13;
    const int blk = L & 8191;
    const float* in = (z == 0) ? q : (z == 1) ? k : v;
    bf16_t* out = (z == 0) ? qo : (z == 1) ? ko : vo;
    const size_t i = ((size_t)blk * 256 + tid) * 4;
    const float4 w = *(const float4*)(in + i);
    bf16x4 o;
    o[0] = (bf16_t)w.x; o[1] = (bf16_t)w.y; o[2] = (bf16_t)w.z; o[3] = (bf16_t)w.w;
    *(bf16x4*)(out + i) = o;
  } else {
    const int t = L - 24576;
    const int z = t >> 8;
    const int wi = t & 255;
    const float* W = (z == 0) ? Wq : (z == 1) ? Wk : Wv;
    bf16_t* Wt = (z == 0) ? Wqt : (z == 1) ? Wkt : Wvt;
    __shared__ float tile[64][65];
    const int n0 = (wi & 15) * 64;
    const int k0 = (wi >> 4) * 64;
#pragma unroll
    for (int it = 0; it < 16; ++it) {
      const int idx = it * 256 + tid;
      const int r = idx >> 6, c = idx & 63;
      tile[r][c] = W[(size_t)(k0 + r) * 1024 + n0 + c];
    }
    __syncthreads();
#pragma unroll
    for (int it = 0; it < 16; ++it) {
      const int idx = it * 256 + tid;
      const int r = idx >> 6, c = idx & 63;
      Wt[(size_t)(n0 + r) * 1024 + k0 + c] = (bf16_t)tile[c][r];
    }
  }
}

extern "C" void kernel_launch(void* const* d_in, const int* in_sizes, int n_in,
                              void* d_out, int out_size, void* d_ws, size_t ws_size,
                              hipStream_t stream) {
  const int B = 4, S = 2048, E = 1024;
  const size_t BSE = (size_t)B * S * E;
  const size_t EE  = (size_t)E * E;

  const float* q_in = (const float*)d_in[0];
  const float* k_in = (const float*)d_in[1];
  const float* v_in = (const float*)d_in[2];
  const float* Wq = (const float*)d_in[3];
  const float* bq = (const float*)d_in[4];
  const float* Wk = (const float*)d_in[5];
  const float* bk = (const float*)d_in[6];
  const float* Wv = (const float*)d_in[7];
  const float* bv = (const float*)d_in[8];
  float* out = (float*)d_out;

  char* ws = (char*)d_ws;
  bf16_t* Wqt = (bf16_t*)ws;                      // 2MB each
  bf16_t* Wkt = Wqt + EE;
  bf16_t* Wvt = Wkt + EE;
  bf16_t* qb  = Wvt + EE;                         // 16.8MB each
  bf16_t* kb  = qb + BSE;
  bf16_t* vb  = kb + BSE;
  bf16_t* qp  = vb + BSE;
  bf16_t* kp  = qp + BSE;
  bf16_t* vT  = kp + BSE;                         // [B][E][S]
  bf16_t* P   = vT + BSE;                         // [B][S][S] 33.5MB; ~140MB

  prep<<<25344, 256, 0, stream>>>(q_in, k_in, v_in, Wq, Wk, Wv,
                                  qb, kb, vb, Wqt, Wkt, Wvt);

  qkv_proj<<<1536, 256, 0, stream>>>(qb, kb, vb, Wqt, Wkt, Wvt,
                                     bq, bk, bv, qp, kp, vT);

  scores_v3<<<512, 512, 0, stream>>>(qp, kp, P);

  pv_v3<<<256, 512, 0, stream>>>(P, vT, out);

  (void)in_sizes; (void)n_in; (void)out_size; (void)ws_size;
}